// Round 6
// baseline (1111.990 us; speedup 1.0000x reference)
//
#include <hip/hip_runtime.h>
#include <hip/hip_bf16.h>

#define NN 50000
#define NE_MAIN 800000
#define NE_CONT 200000
#define NP 50176        // padded histogram size (>= NN)

typedef __attribute__((ext_vector_type(8))) short bf8;   // 8 x bf16 (4 VGPRs)
typedef __attribute__((ext_vector_type(4))) float f4;    // 4 x f32

static __device__ __forceinline__ float bf2f(short s) {
  return __builtin_bit_cast(float, ((unsigned int)(unsigned short)s) << 16);
}
static __device__ __forceinline__ short f2bf(float f) {
  __hip_bfloat16 h = __float2bfloat16(f);   // RNE
  return __builtin_bit_cast(short, h);
}

// bijective XCD-chunked swizzle (m204): consecutive blocks on one XCD get
// consecutive chunk ids -> per-XCD sliding window over sorted-j tiles.
static __device__ __forceinline__ int xcd_swizzle(int bid, int nwg) {
  int xcd = bid & 7;
  int q = nwg >> 3, r = nwg & 7;
  int base = (xcd < r) ? xcd * (q + 1) : r * (q + 1) + (xcd - r) * q;
  return base + (bid >> 3);
}

// ------------------------------------------------------------- zero both ----
__global__ __launch_bounds__(256) void zero2_kernel(f4* __restrict__ p0, int n0,
                                                    f4* __restrict__ p1, int n1) {
  int i = blockIdx.x * 256 + threadIdx.x;
  int stride = gridDim.x * 256;
  f4 z = {0.f, 0.f, 0.f, 0.f};
  for (int k = i; k < n0; k += stride) p0[k] = z;
  for (int k = i; k < n1; k += stride) p1[k] = z;
}

// ------------------------------------------------- counting sort by j ----
__global__ __launch_bounds__(256) void hist2_kernel(const int* __restrict__ gm,
                                                    const int* __restrict__ gc,
                                                    int* __restrict__ hm,
                                                    int* __restrict__ hc, int bm) {
  if ((int)blockIdx.x < bm) {
    int e = blockIdx.x * 256 + threadIdx.x;
    int st = bm * 256;
    for (; e < NE_MAIN; e += st) atomicAdd(&hm[gm[NE_MAIN + e]], 1);
  } else {
    int e = (blockIdx.x - bm) * 256 + threadIdx.x;
    int st = (gridDim.x - bm) * 256;
    for (; e < NE_CONT; e += st) atomicAdd(&hc[gc[NE_CONT + e]], 1);
  }
}

__global__ __launch_bounds__(512) void scan1_kernel(const int* __restrict__ hm,
                                                    int* __restrict__ cm, int* __restrict__ tm,
                                                    const int* __restrict__ hc,
                                                    int* __restrict__ cc, int* __restrict__ tc,
                                                    int n, int nt) {
  __shared__ int buf[2][512];
  const int set = (int)blockIdx.x >= nt;
  const int* hist = set ? hc : hm;
  int* cursor = set ? cc : cm;
  int* tsums  = set ? tc : tm;
  const int blk = set ? blockIdx.x - nt : blockIdx.x;
  int tid = threadIdx.x;
  int i = blk * 512 + tid;
  int v = (i < n) ? hist[i] : 0;
  int cur = 0;
  buf[0][tid] = v;
  __syncthreads();
#pragma unroll
  for (int off = 1; off < 512; off <<= 1) {
    int t = buf[cur][tid];
    if (tid >= off) t += buf[cur][tid - off];
    buf[cur ^ 1][tid] = t;
    cur ^= 1;
    __syncthreads();
  }
  int incl = buf[cur][tid];
  if (i < n) cursor[i] = incl - v;
  if (tid == 511) tsums[blk] = incl;
}

__global__ __launch_bounds__(512) void scan2_kernel(int* __restrict__ tm,
                                                    int* __restrict__ tc, int nt) {
  __shared__ int buf[2][512];
  int* tsums = blockIdx.x ? tc : tm;
  int tid = threadIdx.x;
  int v = (tid < nt) ? tsums[tid] : 0;
  int cur = 0;
  buf[0][tid] = v;
  __syncthreads();
#pragma unroll
  for (int off = 1; off < 512; off <<= 1) {
    int t = buf[cur][tid];
    if (tid >= off) t += buf[cur][tid - off];
    buf[cur ^ 1][tid] = t;
    cur ^= 1;
    __syncthreads();
  }
  if (tid < nt) tsums[tid] = buf[cur][tid] - v;
}

__global__ __launch_bounds__(512) void scan3_kernel(int* __restrict__ cm,
                                                    const int* __restrict__ tm,
                                                    int* __restrict__ cc,
                                                    const int* __restrict__ tc,
                                                    int n, int nt) {
  const int set = (int)blockIdx.x >= nt;
  int* cursor = set ? cc : cm;
  const int* tsums = set ? tc : tm;
  const int blk = set ? blockIdx.x - nt : blockIdx.x;
  int i = blk * 512 + threadIdx.x;
  if (i < n) cursor[i] += tsums[blk];
}

__global__ __launch_bounds__(256) void scatter2_kernel(const int* __restrict__ gm,
                                                       const int* __restrict__ gc,
                                                       int* __restrict__ cm, int* __restrict__ cc,
                                                       int* __restrict__ sim, int* __restrict__ sjm,
                                                       int* __restrict__ sic, int* __restrict__ sjc,
                                                       int bm) {
  if ((int)blockIdx.x < bm) {
    int e = blockIdx.x * 256 + threadIdx.x;
    int st = bm * 256;
    for (; e < NE_MAIN; e += st) {
      int i = gm[e], j = gm[NE_MAIN + e];
      int p = atomicAdd(&cm[j], 1);
      sim[p] = i; sjm[p] = j;
    }
  } else {
    int e = (blockIdx.x - bm) * 256 + threadIdx.x;
    int st = (gridDim.x - bm) * 256;
    for (; e < NE_CONT; e += st) {
      int i = gc[e], j = gc[NE_CONT + e];
      int p = atomicAdd(&cc[j], 1);
      sic[p] = i; sjc[p] = j;
    }
  }
}

// --------------------------------------------------- weight transpose ----
struct WTDesc {
  const float* src[11];
  int K[11];
  int off[11];
};
__global__ __launch_bounds__(128) void wt_kernel(WTDesc d, short* __restrict__ dst) {
  int m = blockIdx.x >> 7;
  int n = blockIdx.x & 127;
  const float* s = d.src[m];
  int K = d.K[m];
  short* o = dst + d.off[m] + (size_t)n * K;
  for (int k = threadIdx.x; k < K; k += 128) o[k] = f2bf(s[(size_t)k * 128 + n]);
}

// ------------------------------------------------------- MFMA helpers ----
// 64-row tile in LDS (bf16, 16B-chunk XOR swizzle: chunk ^= row&7).
// A-frag: row = lane&15 (+rf*16), k = (lane>>4)*8 + j (+ks*32)
// B-frag: col = lane&15 (+cf*16), same k pattern, from WT[N][K].
// C/D  : col = lane&15, row = (lane>>4)*4 + reg  [HW-verified]
template <int K>
static __device__ __forceinline__ void mfma_gemm(const short* __restrict__ sA, int rs16,
                                                 const short* __restrict__ WT,
                                                 int c0, int lane,
                                                 const float* __restrict__ bias,
                                                 f4 (&acc)[4][2]) {
  const int colA = c0 + (lane & 15);
  const int colB = colA + 16;
  if (bias) {
    float ba = bias[colA], bb = bias[colB];
#pragma unroll
    for (int rf = 0; rf < 4; ++rf) {
      acc[rf][0] = (f4){ba, ba, ba, ba};
      acc[rf][1] = (f4){bb, bb, bb, bb};
    }
  } else {
#pragma unroll
    for (int rf = 0; rf < 4; ++rf) {
      acc[rf][0] = (f4){0.f, 0.f, 0.f, 0.f};
      acc[rf][1] = (f4){0.f, 0.f, 0.f, 0.f};
    }
  }
  const int g = lane >> 4;
  const int rowl = lane & 15;
#pragma unroll 4
  for (int ks = 0; ks < (K >> 5); ++ks) {
    bf8 b0 = *reinterpret_cast<const bf8*>(WT + (size_t)colA * K + ks * 32 + g * 8);
    bf8 b1 = *reinterpret_cast<const bf8*>(WT + (size_t)colB * K + ks * 32 + g * 8);
    int chunk = ks * 4 + g;
#pragma unroll
    for (int rf = 0; rf < 4; ++rf) {
      int row = rf * 16 + rowl;
      bf8 a = *reinterpret_cast<const bf8*>(sA + row * rs16 * 8 + ((chunk ^ (row & 7)) << 3));
      acc[rf][0] = __builtin_amdgcn_mfma_f32_16x16x32_bf16(a, b0, acc[rf][0], 0, 0, 0);
      acc[rf][1] = __builtin_amdgcn_mfma_f32_16x16x32_bf16(a, b1, acc[rf][1], 0, 0, 0);
    }
  }
}

template <bool RELU, bool SWZ>
static __device__ __forceinline__ void store_frags(short* __restrict__ dst, int rs16,
                                                   int c0, int lane, const f4 (&acc)[4][2]) {
#pragma unroll
  for (int rf = 0; rf < 4; ++rf)
#pragma unroll
    for (int q = 0; q < 4; ++q) {
      int row = rf * 16 + ((lane >> 4) << 2) + q;
#pragma unroll
      for (int cf = 0; cf < 2; ++cf) {
        int col = c0 + cf * 16 + (lane & 15);
        float v = acc[rf][cf][q];
        if (RELU) v = fmaxf(v, 0.f);
        int idx;
        if (SWZ) idx = row * rs16 * 8 + (((col >> 3) ^ (row & 7)) << 3) + (col & 7);
        else     idx = row * rs16 * 8 + col;
        dst[idx] = f2bf(v);
      }
    }
}

// per-row sum/sumsq over this wave's 32 cols -> sP[wave*64+row]
static __device__ __forceinline__ void ln_rows(const f4 (&acc)[4][2], int lane, int wave,
                                               float2* __restrict__ sP) {
#pragma unroll
  for (int rf = 0; rf < 4; ++rf)
#pragma unroll
    for (int q = 0; q < 4; ++q) {
      float v0 = acc[rf][0][q], v1 = acc[rf][1][q];
      float s = v0 + v1;
      float qq = v0 * v0 + v1 * v1;
      s += __shfl_xor(s, 1);  qq += __shfl_xor(qq, 1);
      s += __shfl_xor(s, 2);  qq += __shfl_xor(qq, 2);
      s += __shfl_xor(s, 4);  qq += __shfl_xor(qq, 4);
      s += __shfl_xor(s, 8);  qq += __shfl_xor(qq, 8);
      if ((lane & 15) == 0) {
        int row = rf * 16 + ((lane >> 4) << 2) + q;
        sP[wave * 64 + row] = make_float2(s, qq);
      }
    }
}

// ------------------------------------------------------------ precompute ----
// xa tables = x@W0_i-slice; xb tables = x@W0_j-slice + b0 (bias folded).
__global__ __launch_bounds__(256) void precompute_kernel(
    const float* __restrict__ x, const short* __restrict__ WTp,
    const float* __restrict__ mb0, const float* __restrict__ cb0,
    short* __restrict__ xa_m, short* __restrict__ xb_m,
    short* __restrict__ xa_c, short* __restrict__ xb_c) {
  __shared__ __align__(16) short sA[64 * 128];
  __shared__ __align__(16) short sOut[64 * 128];
  const int tid = threadIdx.x;
  const int lane = tid & 63, wave = tid >> 6;
  const int c0 = wave * 32;
  const int n0 = blockIdx.x * 64;

#pragma unroll
  for (int it = 0; it < 4; ++it) {
    int s = it * 256 + tid;
    int e = s >> 4, c = s & 15;
    int n = n0 + e;
    f4 u0 = {0.f, 0.f, 0.f, 0.f}, u1 = {0.f, 0.f, 0.f, 0.f};
    if (n < NN) {
      u0 = *reinterpret_cast<const f4*>(x + (size_t)n * 128 + c * 8);
      u1 = *reinterpret_cast<const f4*>(x + (size_t)n * 128 + c * 8 + 4);
    }
    bf8 o;
#pragma unroll
    for (int j = 0; j < 4; ++j) { o[j] = f2bf(u0[j]); o[j + 4] = f2bf(u1[j]); }
    *reinterpret_cast<bf8*>(sA + e * 128 + ((c ^ (e & 7)) << 3)) = o;
  }
  __syncthreads();

  short* dsts[4] = {xa_m, xb_m, xa_c, xb_c};
  const float* biases[4] = {nullptr, mb0, nullptr, cb0};
#pragma unroll 1
  for (int o = 0; o < 4; ++o) {
    f4 acc[4][2];
    mfma_gemm<128>(sA, 16, WTp + o * 16384, c0, lane, biases[o], acc);
    store_frags<false, false>(sOut, 16, c0, lane, acc);
    __syncthreads();
    short* dst = dsts[o];
#pragma unroll
    for (int it = 0; it < 4; ++it) {
      int s = it * 256 + tid;
      int e = s >> 4, c = s & 15;
      int n = n0 + e;
      if (n < NN)
        *reinterpret_cast<bf8*>(dst + (size_t)n * 128 + c * 8) =
            *reinterpret_cast<const bf8*>(sOut + e * 128 + c * 8);
    }
    __syncthreads();
  }
}

// ------------------------------------------------------- fused edge MLP ----
struct EdgeArgs {
  const int* si; const int* sj;
  const short* xa; const short* xb;
  const float* pp;
  const float* W0f;
  const short* WT1; const float* b1;
  const short* WT2; const float* b2;
  float* agg;
  int ntiles; int nchunks; int nf;
};

template <int NF>
static __device__ __forceinline__ void stage_h0(short* __restrict__ sA,
                                                const bf8 (&pxa)[4], const bf8 (&pxb)[4],
                                                const float (* __restrict__ sFc)[8],
                                                const float* __restrict__ W0f, int tid) {
#pragma unroll
  for (int it = 0; it < 4; ++it) {
    int s = it * 256 + tid;
    int e = s >> 4, c = s & 15;
    float h[8];
#pragma unroll
    for (int jj = 0; jj < 8; ++jj) h[jj] = bf2f(pxa[it][jj]) + bf2f(pxb[it][jj]);
#pragma unroll
    for (int q = 0; q < NF; ++q) {
      float fq = sFc[e][q];
      f4 w0 = *reinterpret_cast<const f4*>(W0f + q * 128 + c * 8);
      f4 w1 = *reinterpret_cast<const f4*>(W0f + q * 128 + c * 8 + 4);
#pragma unroll
      for (int jj = 0; jj < 4; ++jj) {
        h[jj]     = fmaf(fq, w0[jj], h[jj]);
        h[jj + 4] = fmaf(fq, w1[jj], h[jj + 4]);
      }
    }
    bf8 o;
#pragma unroll
    for (int jj = 0; jj < 8; ++jj) o[jj] = f2bf(fmaxf(h[jj], 0.f));
    *reinterpret_cast<bf8*>(sA + e * 128 + ((c ^ (e & 7)) << 3)) = o;
  }
}

// 2 tiles per block (preserves per-XCD sliding window over sorted j);
// tile1's xa/xb gather issues under tile0's GEMM2+LN+reduce.
__global__ __launch_bounds__(256, 4) void edge_fused_kernel(EdgeArgs am, EdgeArgs ac,
                                                            int chunks_m) {
  __shared__ __align__(16) short sAB[2 * 64 * 128];   // h0 | h1, reused as f32 T tile
  __shared__ int sI[2][64], sJ[2][64];
  __shared__ float sF[2][64][8];
  __shared__ float2 sP[4 * 64];
  __shared__ float2 sStats[64];
  const int tid = threadIdx.x;
  const int lane = tid & 63, wave = tid >> 6;
  const int c0 = wave * 32;
  short* sA = sAB;
  short* sB = sAB + 64 * 128;
  float* sT = reinterpret_cast<float*>(sAB);

  EdgeArgs A;
  int lb;
  if ((int)blockIdx.x < chunks_m) { A = am; lb = blockIdx.x; }
  else                            { A = ac; lb = blockIdx.x - chunks_m; }
  lb = xcd_swizzle(lb, A.nchunks);   // contiguous chunk range per XCD, window preserved
  const int t0 = lb * 2;
  const int t1 = min(t0 + 2, A.ntiles);
  const int nf = A.nf;

  // ---- prologue: idx/pos/feats for tile t0 ----
  int cur = 0;
  if (tid < 64) {
    int e = t0 * 64 + tid;
    int i = A.si[e], j = A.sj[e];
    sI[0][tid] = i; sJ[0][tid] = j;
    const float* pi = A.pp + (size_t)i * 6;
    const float* pj = A.pp + (size_t)j * 6;
    float d0 = pi[0] - pj[0], d1 = pi[1] - pj[1], d2 = pi[2] - pj[2];
    float w0 = pi[3] - pj[3], w1 = pi[4] - pj[4], w2 = pi[5] - pj[5];
    float* sf = sF[0][tid];
    if (nf == 8) {
      sf[0] = d0; sf[1] = d1; sf[2] = d2; sf[3] = sqrtf(d0 * d0 + d1 * d1 + d2 * d2);
      sf[4] = w0; sf[5] = w1; sf[6] = w2; sf[7] = sqrtf(w0 * w0 + w1 * w1 + w2 * w2);
    } else {
      sf[0] = w0; sf[1] = w1; sf[2] = w2; sf[3] = sqrtf(w0 * w0 + w1 * w1 + w2 * w2);
    }
  }
  __syncthreads();

  bf8 pxa[4], pxb[4];
#pragma unroll
  for (int it = 0; it < 4; ++it) {
    int s = it * 256 + tid, e = s >> 4, c = s & 15;
    pxa[it] = *reinterpret_cast<const bf8*>(A.xa + (size_t)sI[0][e] * 128 + c * 8);
    pxb[it] = *reinterpret_cast<const bf8*>(A.xb + (size_t)sJ[0][e] * 128 + c * 8);
  }

  for (int tt = t0; tt < t1; ++tt) {
    const bool nb = (tt + 1 < t1);
    int ni = 0, nj2 = 0;
    if (nb && tid < 64) {
      int e = (tt + 1) * 64 + tid;
      ni = A.si[e];
      nj2 = A.sj[e];
    }
    if (nf == 8) stage_h0<8>(sA, pxa, pxb, sF[cur], A.W0f, tid);
    else         stage_h0<4>(sA, pxa, pxb, sF[cur], A.W0f, tid);
    __syncthreads();                                   // A: h0 visible
    if (nb && tid < 64) {
      int nxt = cur ^ 1;
      sI[nxt][tid] = ni; sJ[nxt][tid] = nj2;
      const float* pi = A.pp + (size_t)ni * 6;
      const float* pj = A.pp + (size_t)nj2 * 6;
      float d0 = pi[0] - pj[0], d1 = pi[1] - pj[1], d2 = pi[2] - pj[2];
      float w0 = pi[3] - pj[3], w1 = pi[4] - pj[4], w2 = pi[5] - pj[5];
      float* sf = sF[nxt][tid];
      if (nf == 8) {
        sf[0] = d0; sf[1] = d1; sf[2] = d2; sf[3] = sqrtf(d0 * d0 + d1 * d1 + d2 * d2);
        sf[4] = w0; sf[5] = w1; sf[6] = w2; sf[7] = sqrtf(w0 * w0 + w1 * w1 + w2 * w2);
      } else {
        sf[0] = w0; sf[1] = w1; sf[2] = w2; sf[3] = sqrtf(w0 * w0 + w1 * w1 + w2 * w2);
      }
    }
    f4 acc[4][2];
    mfma_gemm<128>(sA, 16, A.WT1, c0, lane, A.b1, acc);   // h1 = relu(h0)@W1+b1
    store_frags<true, true>(sB, 16, c0, lane, acc);
    __syncthreads();                                   // B: h1 + sI[nxt] visible
    if (nb) {
      int nxt = cur ^ 1;
#pragma unroll
      for (int it = 0; it < 4; ++it) {
        int s = it * 256 + tid, e = s >> 4, c = s & 15;
        pxa[it] = *reinterpret_cast<const bf8*>(A.xa + (size_t)sI[nxt][e] * 128 + c * 8);
        pxb[it] = *reinterpret_cast<const bf8*>(A.xb + (size_t)sJ[nxt][e] * 128 + c * 8);
      }
    }
    mfma_gemm<128>(sB, 16, A.WT2, c0, lane, A.b2, acc);   // h2 = relu(h1)@W2+b2
    ln_rows(acc, lane, wave, sP);
    __syncthreads();                                   // C
    if (tid < 64) {
      float s = 0.f, qq = 0.f;
#pragma unroll
      for (int w = 0; w < 4; ++w) { s += sP[w * 64 + tid].x; qq += sP[w * 64 + tid].y; }
      float mean = s * (1.f / 128.f);
      float var = qq * (1.f / 128.f) - mean * mean;
      sStats[tid] = make_float2(mean, rsqrtf(var + 1e-5f));
    }
    __syncthreads();                                   // D
    // normalized h2 -> f32 T tile (bank-rotated: conflict-free)
#pragma unroll
    for (int rf = 0; rf < 4; ++rf)
#pragma unroll
      for (int qq2 = 0; qq2 < 4; ++qq2) {
        int row = rf * 16 + ((lane >> 4) << 2) + qq2;
        float mean = sStats[row].x, rn = sStats[row].y;
#pragma unroll
        for (int cf = 0; cf < 2; ++cf) {
          int col = c0 + cf * 16 + (lane & 15);
          sT[row * 128 + ((col + 4 * row) & 127)] = (acc[rf][cf][qq2] - mean) * rn;
        }
      }
    __syncthreads();                                   // E
    // segmented column sums: one atomic per (j-run, col)
    {
      int grp = tid >> 7, c = tid & 127;
      int r0g = grp * 32;
      float accum = 0.f;
#pragma unroll 4
      for (int rr = r0g; rr < r0g + 32; ++rr) {
        accum += sT[rr * 128 + ((c + 4 * rr) & 127)];
        bool flush = (rr == r0g + 31) || (sJ[cur][rr + 1] != sJ[cur][rr]);
        if (flush) {
          unsafeAtomicAdd(A.agg + (size_t)sJ[cur][rr] * 128 + c, accum);
          accum = 0.f;
        }
      }
    }
    __syncthreads();                                   // F: T reads done before next h0
    cur ^= 1;
  }
}

// ------------------------------------------------------------ node MLP ----
__global__ __launch_bounds__(256) void node_kernel(
    const float* __restrict__ x,
    const float* __restrict__ agg_m, const float* __restrict__ agg_c,
    const short* __restrict__ WT0, const float* __restrict__ b0v,
    const short* __restrict__ WT1, const float* __restrict__ b1v,
    const short* __restrict__ WT2, const float* __restrict__ b2v,
    float* __restrict__ out) {
  __shared__ __align__(16) short sA[64 * 384];
  __shared__ float2 sP[4 * 64];
  __shared__ float2 sStats[64];
  const int tid = threadIdx.x;
  const int lane = tid & 63, wave = tid >> 6;
  const int c0 = wave * 32;
  const int n0 = blockIdx.x * 64;

#pragma unroll
  for (int p = 0; p < 3; ++p) {
    const float* src = (p == 0) ? x : (p == 1) ? agg_m : agg_c;
#pragma unroll
    for (int it = 0; it < 4; ++it) {
      int s = it * 256 + tid;
      int e = s >> 4, cl = s & 15;
      int n = n0 + e;
      f4 u0 = {0.f, 0.f, 0.f, 0.f}, u1 = {0.f, 0.f, 0.f, 0.f};
      if (n < NN) {
        u0 = *reinterpret_cast<const f4*>(src + (size_t)n * 128 + cl * 8);
        u1 = *reinterpret_cast<const f4*>(src + (size_t)n * 128 + cl * 8 + 4);
      }
      bf8 o;
#pragma unroll
      for (int j = 0; j < 4; ++j) { o[j] = f2bf(u0[j]); o[j + 4] = f2bf(u1[j]); }
      int c = p * 16 + cl;
      *reinterpret_cast<bf8*>(sA + e * 384 + ((c ^ (e & 7)) << 3)) = o;
    }
  }
  __syncthreads();

  f4 acc[4][2];
  mfma_gemm<384>(sA, 48, WT0, c0, lane, b0v, acc);
  __syncthreads();
  store_frags<true, true>(sA, 16, c0, lane, acc);
  __syncthreads();
  mfma_gemm<128>(sA, 16, WT1, c0, lane, b1v, acc);
  __syncthreads();
  store_frags<true, true>(sA + 8192, 16, c0, lane, acc);
  __syncthreads();
  mfma_gemm<128>(sA + 8192, 16, WT2, c0, lane, b2v, acc);

  ln_rows(acc, lane, wave, sP);
  __syncthreads();
  if (tid < 64) {
    float s = 0.f, qq = 0.f;
#pragma unroll
    for (int w = 0; w < 4; ++w) { s += sP[w * 64 + tid].x; qq += sP[w * 64 + tid].y; }
    float mean = s * (1.f / 128.f);
    float var = qq * (1.f / 128.f) - mean * mean;
    sStats[tid] = make_float2(mean, rsqrtf(var + 1e-5f));
  }
  __syncthreads();

#pragma unroll
  for (int rf = 0; rf < 4; ++rf)
#pragma unroll
    for (int q = 0; q < 4; ++q) {
      int row = rf * 16 + ((lane >> 4) << 2) + q;
      int n = n0 + row;
      if (n < NN) {
        float mean = sStats[row].x, rn = sStats[row].y;
#pragma unroll
        for (int cf = 0; cf < 2; ++cf) {
          int col = c0 + cf * 16 + (lane & 15);
          float xv = x[(size_t)n * 128 + col];
          out[(size_t)n * 128 + col] = (acc[rf][cf][q] - mean) * rn + xv;
        }
      }
    }
}

// -------------------------------------------------------------- launch ----
extern "C" void kernel_launch(void* const* d_in, const int* in_sizes, int n_in,
                              void* d_out, int out_size, void* d_ws, size_t ws_size,
                              hipStream_t stream) {
  const float* x   = (const float*)d_in[0];
  const int*   g   = (const int*)d_in[1];
  const int*   cgr = (const int*)d_in[2];
  const float* pp  = (const float*)d_in[3];
  const float* mW0 = (const float*)d_in[4];
  const float* mb0 = (const float*)d_in[5];
  const float* mW1 = (const float*)d_in[6];
  const float* mb1 = (const float*)d_in[7];
  const float* mW2 = (const float*)d_in[8];
  const float* mb2 = (const float*)d_in[9];
  const float* cW0 = (const float*)d_in[10];
  const float* cb0 = (const float*)d_in[11];
  const float* cW1 = (const float*)d_in[12];
  const float* cb1 = (const float*)d_in[13];
  const float* cW2 = (const float*)d_in[14];
  const float* cb2 = (const float*)d_in[15];
  const float* nW0 = (const float*)d_in[16];
  const float* nb0 = (const float*)d_in[17];
  const float* nW1 = (const float*)d_in[18];
  const float* nb1 = (const float*)d_in[19];
  const float* nW2 = (const float*)d_in[20];
  const float* nb2 = (const float*)d_in[21];
  float* out = (float*)d_out;

  // ---- weight transpose packing (compute total size FIRST) ----
  WTDesc d;
  const float* srcs[11] = {mW1, mW2, cW1, cW2, nW0, nW1, nW2,
                           mW0 + 8 * 128, mW0 + 136 * 128, cW0 + 4 * 128, cW0 + 132 * 128};
  int Ks[11] = {128, 128, 128, 128, 384, 128, 128, 128, 128, 128, 128};
  int off = 0;
  for (int m = 0; m < 11; ++m) { d.src[m] = srcs[m]; d.K[m] = Ks[m]; d.off[m] = off; off += Ks[m] * 128; }

  // ---- workspace layout ----
  char* ws = (char*)d_ws;
  const size_t TBL = (size_t)NN * 128 * 2;        // 12.8 MB (bf16 table)
  const size_t AGG = (size_t)NN * 128 * 4;        // 25.6 MB (f32 agg)
  short* xa_m = (short*)(ws);
  short* xb_m = (short*)(ws + TBL);
  short* xa_c = (short*)(ws + 2 * TBL);
  short* xb_c = (short*)(ws + 3 * TBL);
  float* agg_m = (float*)(ws + 4 * TBL);
  float* agg_c = (float*)(ws + 4 * TBL + AGG);
  short* wt = (short*)(ws + 4 * TBL + 2 * AGG);
  char* ib = ws + 4 * TBL + 2 * AGG + (size_t)off * 2;   // after FULL wt buffer
  int* hist_m   = (int*)(ib);
  int* hist_c   = hist_m + NP;
  int* cursor_m = hist_c + NP;
  int* cursor_c = cursor_m + NP;
  int* tsum_m   = cursor_c + NP;
  int* tsum_c   = tsum_m + 128;
  int* si_m     = tsum_c + 128;
  int* sj_m     = si_m + NE_MAIN;
  int* si_c     = sj_m + NE_MAIN;
  int* sj_c     = si_c + NE_CONT;

  short* wt1_m = wt + d.off[0];
  short* wt2_m = wt + d.off[1];
  short* wt1_c = wt + d.off[2];
  short* wt2_c = wt + d.off[3];
  short* wtn0  = wt + d.off[4];
  short* wtn1  = wt + d.off[5];
  short* wtn2  = wt + d.off[6];
  short* wtp   = wt + d.off[7];

  const int NT = (NN + 511) / 512;   // 98 scan tiles per set

  wt_kernel<<<11 * 128, 128, 0, stream>>>(d, wt);
  zero2_kernel<<<2048, 256, 0, stream>>>((f4*)agg_m, (int)(2 * (size_t)NN * 128 / 4),
                                         (f4*)hist_m, 2 * NP / 4);

  // counting sort by j (both edge sets, merged launches)
  hist2_kernel<<<1024 + 256, 256, 0, stream>>>(g, cgr, hist_m, hist_c, 1024);
  scan1_kernel<<<2 * NT, 512, 0, stream>>>(hist_m, cursor_m, tsum_m,
                                           hist_c, cursor_c, tsum_c, NN, NT);
  scan2_kernel<<<2, 512, 0, stream>>>(tsum_m, tsum_c, NT);
  scan3_kernel<<<2 * NT, 512, 0, stream>>>(cursor_m, tsum_m, cursor_c, tsum_c, NN, NT);
  scatter2_kernel<<<1024 + 256, 256, 0, stream>>>(g, cgr, cursor_m, cursor_c,
                                                  si_m, sj_m, si_c, sj_c, 1024);

  precompute_kernel<<<(NN + 63) / 64, 256, 0, stream>>>(x, wtp, mb0, cb0,
                                                        xa_m, xb_m, xa_c, xb_c);

  const int TIL_M = NE_MAIN / 64, TIL_C = NE_CONT / 64;
  const int CHK_M = (TIL_M + 1) / 2, CHK_C = (TIL_C + 1) / 2;
  EdgeArgs am = {si_m, sj_m, xa_m, xb_m, pp, mW0, wt1_m, mb1, wt2_m, mb2,
                 agg_m, TIL_M, CHK_M, 8};
  EdgeArgs ac = {si_c, sj_c, xa_c, xb_c, pp, cW0, wt1_c, cb1, wt2_c, cb2,
                 agg_c, TIL_C, CHK_C, 4};
  edge_fused_kernel<<<CHK_M + CHK_C, 256, 0, stream>>>(am, ac, CHK_M);

  node_kernel<<<(NN + 63) / 64, 256, 0, stream>>>(x, agg_m, agg_c,
                                                  wtn0, nb0, wtn1, nb1, wtn2, nb2, out);
}

// Round 7
// 657.549 us; speedup vs baseline: 1.6911x; 1.6911x over previous
//
#include <hip/hip_runtime.h>
#include <hip/hip_bf16.h>

#define NN 50000
#define NE_MAIN 800000
#define NE_CONT 200000
#define NP 50176        // padded histogram size (>= NN)

typedef __attribute__((ext_vector_type(8))) short bf8;   // 8 x bf16 (4 VGPRs)
typedef __attribute__((ext_vector_type(4))) float f4;    // 4 x f32

static __device__ __forceinline__ float bf2f(short s) {
  return __builtin_bit_cast(float, ((unsigned int)(unsigned short)s) << 16);
}
static __device__ __forceinline__ short f2bf(float f) {
  __hip_bfloat16 h = __float2bfloat16(f);   // RNE
  return __builtin_bit_cast(short, h);
}

// bijective XCD-chunked swizzle (m204): consecutive blocks on one XCD get
// consecutive tiles -> per-XCD sliding window over sorted-j tiles.
static __device__ __forceinline__ int xcd_swizzle(int bid, int nwg) {
  int xcd = bid & 7;
  int q = nwg >> 3, r = nwg & 7;
  int base = (xcd < r) ? xcd * (q + 1) : r * (q + 1) + (xcd - r) * q;
  return base + (bid >> 3);
}

// ------------------------------------------------------------- zero both ----
__global__ __launch_bounds__(256) void zero2_kernel(f4* __restrict__ p0, int n0,
                                                    f4* __restrict__ p1, int n1) {
  int i = blockIdx.x * 256 + threadIdx.x;
  int stride = gridDim.x * 256;
  f4 z = {0.f, 0.f, 0.f, 0.f};
  for (int k = i; k < n0; k += stride) p0[k] = z;
  for (int k = i; k < n1; k += stride) p1[k] = z;
}

// ------------------------------------------------- counting sort by j ----
__global__ __launch_bounds__(256) void hist2_kernel(const int* __restrict__ gm,
                                                    const int* __restrict__ gc,
                                                    int* __restrict__ hm,
                                                    int* __restrict__ hc, int bm) {
  if ((int)blockIdx.x < bm) {
    int e = blockIdx.x * 256 + threadIdx.x;
    int st = bm * 256;
    for (; e < NE_MAIN; e += st) atomicAdd(&hm[gm[NE_MAIN + e]], 1);
  } else {
    int e = (blockIdx.x - bm) * 256 + threadIdx.x;
    int st = (gridDim.x - bm) * 256;
    for (; e < NE_CONT; e += st) atomicAdd(&hc[gc[NE_CONT + e]], 1);
  }
}

__global__ __launch_bounds__(512) void scan1_kernel(const int* __restrict__ hm,
                                                    int* __restrict__ cm, int* __restrict__ tm,
                                                    const int* __restrict__ hc,
                                                    int* __restrict__ cc, int* __restrict__ tc,
                                                    int n, int nt) {
  __shared__ int buf[2][512];
  const int set = (int)blockIdx.x >= nt;
  const int* hist = set ? hc : hm;
  int* cursor = set ? cc : cm;
  int* tsums  = set ? tc : tm;
  const int blk = set ? blockIdx.x - nt : blockIdx.x;
  int tid = threadIdx.x;
  int i = blk * 512 + tid;
  int v = (i < n) ? hist[i] : 0;
  int cur = 0;
  buf[0][tid] = v;
  __syncthreads();
#pragma unroll
  for (int off = 1; off < 512; off <<= 1) {
    int t = buf[cur][tid];
    if (tid >= off) t += buf[cur][tid - off];
    buf[cur ^ 1][tid] = t;
    cur ^= 1;
    __syncthreads();
  }
  int incl = buf[cur][tid];
  if (i < n) cursor[i] = incl - v;
  if (tid == 511) tsums[blk] = incl;
}

__global__ __launch_bounds__(512) void scan2_kernel(int* __restrict__ tm,
                                                    int* __restrict__ tc, int nt) {
  __shared__ int buf[2][512];
  int* tsums = blockIdx.x ? tc : tm;
  int tid = threadIdx.x;
  int v = (tid < nt) ? tsums[tid] : 0;
  int cur = 0;
  buf[0][tid] = v;
  __syncthreads();
#pragma unroll
  for (int off = 1; off < 512; off <<= 1) {
    int t = buf[cur][tid];
    if (tid >= off) t += buf[cur][tid - off];
    buf[cur ^ 1][tid] = t;
    cur ^= 1;
    __syncthreads();
  }
  if (tid < nt) tsums[tid] = buf[cur][tid] - v;
}

__global__ __launch_bounds__(512) void scan3_kernel(int* __restrict__ cm,
                                                    const int* __restrict__ tm,
                                                    int* __restrict__ cc,
                                                    const int* __restrict__ tc,
                                                    int n, int nt) {
  const int set = (int)blockIdx.x >= nt;
  int* cursor = set ? cc : cm;
  const int* tsums = set ? tc : tm;
  const int blk = set ? blockIdx.x - nt : blockIdx.x;
  int i = blk * 512 + threadIdx.x;
  if (i < n) cursor[i] += tsums[blk];
}

__global__ __launch_bounds__(256) void scatter2_kernel(const int* __restrict__ gm,
                                                       const int* __restrict__ gc,
                                                       int* __restrict__ cm, int* __restrict__ cc,
                                                       int* __restrict__ sim, int* __restrict__ sjm,
                                                       int* __restrict__ sic, int* __restrict__ sjc,
                                                       int bm) {
  if ((int)blockIdx.x < bm) {
    int e = blockIdx.x * 256 + threadIdx.x;
    int st = bm * 256;
    for (; e < NE_MAIN; e += st) {
      int i = gm[e], j = gm[NE_MAIN + e];
      int p = atomicAdd(&cm[j], 1);
      sim[p] = i; sjm[p] = j;
    }
  } else {
    int e = (blockIdx.x - bm) * 256 + threadIdx.x;
    int st = (gridDim.x - bm) * 256;
    for (; e < NE_CONT; e += st) {
      int i = gc[e], j = gc[NE_CONT + e];
      int p = atomicAdd(&cc[j], 1);
      sic[p] = i; sjc[p] = j;
    }
  }
}

// --------------------------------------------------- weight transpose ----
struct WTDesc {
  const float* src[11];
  int K[11];
  int off[11];
};
__global__ __launch_bounds__(128) void wt_kernel(WTDesc d, short* __restrict__ dst) {
  int m = blockIdx.x >> 7;
  int n = blockIdx.x & 127;
  const float* s = d.src[m];
  int K = d.K[m];
  short* o = dst + d.off[m] + (size_t)n * K;
  for (int k = threadIdx.x; k < K; k += 128) o[k] = f2bf(s[(size_t)k * 128 + n]);
}

// ------------------------------------------------------- MFMA helpers ----
// 64-row tile in LDS (bf16, 16B-chunk XOR swizzle: chunk ^= row&7).
// A-frag: row = lane&15 (+rf*16), k = (lane>>4)*8 + j (+ks*32)
// B-frag: col = lane&15 (+cf*16), same k pattern, from WT[N][K].
// C/D  : col = lane&15, row = (lane>>4)*4 + reg  [HW-verified]
template <int K>
static __device__ __forceinline__ void mfma_gemm(const short* __restrict__ sA, int rs16,
                                                 const short* __restrict__ WT,
                                                 int c0, int lane,
                                                 const float* __restrict__ bias,
                                                 f4 (&acc)[4][2]) {
  const int colA = c0 + (lane & 15);
  const int colB = colA + 16;
  if (bias) {
    float ba = bias[colA], bb = bias[colB];
#pragma unroll
    for (int rf = 0; rf < 4; ++rf) {
      acc[rf][0] = (f4){ba, ba, ba, ba};
      acc[rf][1] = (f4){bb, bb, bb, bb};
    }
  } else {
#pragma unroll
    for (int rf = 0; rf < 4; ++rf) {
      acc[rf][0] = (f4){0.f, 0.f, 0.f, 0.f};
      acc[rf][1] = (f4){0.f, 0.f, 0.f, 0.f};
    }
  }
  const int g = lane >> 4;
  const int rowl = lane & 15;
#pragma unroll 4
  for (int ks = 0; ks < (K >> 5); ++ks) {
    bf8 b0 = *reinterpret_cast<const bf8*>(WT + (size_t)colA * K + ks * 32 + g * 8);
    bf8 b1 = *reinterpret_cast<const bf8*>(WT + (size_t)colB * K + ks * 32 + g * 8);
    int chunk = ks * 4 + g;
#pragma unroll
    for (int rf = 0; rf < 4; ++rf) {
      int row = rf * 16 + rowl;
      bf8 a = *reinterpret_cast<const bf8*>(sA + row * rs16 * 8 + ((chunk ^ (row & 7)) << 3));
      acc[rf][0] = __builtin_amdgcn_mfma_f32_16x16x32_bf16(a, b0, acc[rf][0], 0, 0, 0);
      acc[rf][1] = __builtin_amdgcn_mfma_f32_16x16x32_bf16(a, b1, acc[rf][1], 0, 0, 0);
    }
  }
}

template <bool RELU, bool SWZ>
static __device__ __forceinline__ void store_frags(short* __restrict__ dst, int rs16,
                                                   int c0, int lane, const f4 (&acc)[4][2]) {
#pragma unroll
  for (int rf = 0; rf < 4; ++rf)
#pragma unroll
    for (int q = 0; q < 4; ++q) {
      int row = rf * 16 + ((lane >> 4) << 2) + q;
#pragma unroll
      for (int cf = 0; cf < 2; ++cf) {
        int col = c0 + cf * 16 + (lane & 15);
        float v = acc[rf][cf][q];
        if (RELU) v = fmaxf(v, 0.f);
        int idx;
        if (SWZ) idx = row * rs16 * 8 + (((col >> 3) ^ (row & 7)) << 3) + (col & 7);
        else     idx = row * rs16 * 8 + col;
        dst[idx] = f2bf(v);
      }
    }
}

// per-row sum/sumsq over this wave's 32 cols -> sP[wave*64+row]
static __device__ __forceinline__ void ln_rows(const f4 (&acc)[4][2], int lane, int wave,
                                               float2* __restrict__ sP) {
#pragma unroll
  for (int rf = 0; rf < 4; ++rf)
#pragma unroll
    for (int q = 0; q < 4; ++q) {
      float v0 = acc[rf][0][q], v1 = acc[rf][1][q];
      float s = v0 + v1;
      float qq = v0 * v0 + v1 * v1;
      s += __shfl_xor(s, 1);  qq += __shfl_xor(qq, 1);
      s += __shfl_xor(s, 2);  qq += __shfl_xor(qq, 2);
      s += __shfl_xor(s, 4);  qq += __shfl_xor(qq, 4);
      s += __shfl_xor(s, 8);  qq += __shfl_xor(qq, 8);
      if ((lane & 15) == 0) {
        int row = rf * 16 + ((lane >> 4) << 2) + q;
        sP[wave * 64 + row] = make_float2(s, qq);
      }
    }
}

// ------------------------------------------------------------ precompute ----
// xa tables = x@W0_i-slice; xb tables = x@W0_j-slice + b0 (bias folded).
__global__ __launch_bounds__(256) void precompute_kernel(
    const float* __restrict__ x, const short* __restrict__ WTp,
    const float* __restrict__ mb0, const float* __restrict__ cb0,
    short* __restrict__ xa_m, short* __restrict__ xb_m,
    short* __restrict__ xa_c, short* __restrict__ xb_c) {
  __shared__ __align__(16) short sA[64 * 128];
  __shared__ __align__(16) short sOut[64 * 128];
  const int tid = threadIdx.x;
  const int lane = tid & 63, wave = tid >> 6;
  const int c0 = wave * 32;
  const int n0 = blockIdx.x * 64;

#pragma unroll
  for (int it = 0; it < 4; ++it) {
    int s = it * 256 + tid;
    int e = s >> 4, c = s & 15;
    int n = n0 + e;
    f4 u0 = {0.f, 0.f, 0.f, 0.f}, u1 = {0.f, 0.f, 0.f, 0.f};
    if (n < NN) {
      u0 = *reinterpret_cast<const f4*>(x + (size_t)n * 128 + c * 8);
      u1 = *reinterpret_cast<const f4*>(x + (size_t)n * 128 + c * 8 + 4);
    }
    bf8 o;
#pragma unroll
    for (int j = 0; j < 4; ++j) { o[j] = f2bf(u0[j]); o[j + 4] = f2bf(u1[j]); }
    *reinterpret_cast<bf8*>(sA + e * 128 + ((c ^ (e & 7)) << 3)) = o;
  }
  __syncthreads();

  short* dsts[4] = {xa_m, xb_m, xa_c, xb_c};
  const float* biases[4] = {nullptr, mb0, nullptr, cb0};
#pragma unroll 1
  for (int o = 0; o < 4; ++o) {
    f4 acc[4][2];
    mfma_gemm<128>(sA, 16, WTp + o * 16384, c0, lane, biases[o], acc);
    store_frags<false, false>(sOut, 16, c0, lane, acc);
    __syncthreads();
    short* dst = dsts[o];
#pragma unroll
    for (int it = 0; it < 4; ++it) {
      int s = it * 256 + tid;
      int e = s >> 4, c = s & 15;
      int n = n0 + e;
      if (n < NN)
        *reinterpret_cast<bf8*>(dst + (size_t)n * 128 + c * 8) =
            *reinterpret_cast<const bf8*>(sOut + e * 128 + c * 8);
    }
    __syncthreads();
  }
}

// ------------------------------------------------------------ edge MLP ----
// R4 structure: ONE tile per block, dispatch-order sliding window, inline
// gather. NEW: single 16KB LDS tile reused in place (h0 -> h1 -> bf16 T)
// -> ~21KB LDS -> 7 blocks/CU (was 4).
template <int NF>
__global__ __launch_bounds__(256) void edge_kernel(
    const int* __restrict__ si, const int* __restrict__ sjv,
    const float* __restrict__ pp,
    const short* __restrict__ xa, const short* __restrict__ xb,
    const float* __restrict__ W0f,
    const short* __restrict__ WT1, const float* __restrict__ b1v,
    const short* __restrict__ WT2, const float* __restrict__ b2v,
    float* __restrict__ agg) {
  __shared__ __align__(16) short sA[64 * 128];   // h0 -> h1 -> normalized-h2 (bf16)
  __shared__ int sI[64], sJ[64];
  __shared__ float sF[64][NF];
  __shared__ float2 sP[4 * 64];
  __shared__ float2 sStats[64];
  const int tid = threadIdx.x;
  const int lane = tid & 63, wave = tid >> 6;
  const int c0 = wave * 32;
  const int base = xcd_swizzle(blockIdx.x, gridDim.x) * 64;

  if (tid < 64) {
    int e = base + tid;
    int i = si[e], j = sjv[e];
    sI[tid] = i; sJ[tid] = j;
    const float* pi = pp + (size_t)i * 6;
    const float* pj = pp + (size_t)j * 6;
    if (NF == 8) {
      float d0 = pi[0] - pj[0], d1 = pi[1] - pj[1], d2 = pi[2] - pj[2];
      sF[tid][0] = d0; sF[tid][1] = d1; sF[tid][2] = d2;
      sF[tid][3] = sqrtf(d0 * d0 + d1 * d1 + d2 * d2);
      float w0 = pi[3] - pj[3], w1 = pi[4] - pj[4], w2 = pi[5] - pj[5];
      sF[tid][4] = w0; sF[tid][5] = w1; sF[tid][6] = w2;
      sF[tid][7] = sqrtf(w0 * w0 + w1 * w1 + w2 * w2);
    } else {
      float w0 = pi[3] - pj[3], w1 = pi[4] - pj[4], w2 = pi[5] - pj[5];
      sF[tid][0] = w0; sF[tid][1] = w1; sF[tid][2] = w2;
      sF[tid][3] = sqrtf(w0 * w0 + w1 * w1 + w2 * w2);
    }
  }
  __syncthreads();

  // stage h0 = relu(xa[i] + xb[j](b0 folded) + feat@W0f) as bf16 (swizzled)
#pragma unroll
  for (int it = 0; it < 4; ++it) {
    int s = it * 256 + tid;
    int e = s >> 4, c = s & 15;
    bf8 va = *reinterpret_cast<const bf8*>(xa + (size_t)sI[e] * 128 + c * 8);
    bf8 vb = *reinterpret_cast<const bf8*>(xb + (size_t)sJ[e] * 128 + c * 8);
    float h[8];
#pragma unroll
    for (int jj = 0; jj < 8; ++jj) h[jj] = bf2f(va[jj]) + bf2f(vb[jj]);
#pragma unroll
    for (int q = 0; q < NF; ++q) {
      float fq = sF[e][q];
      f4 w0 = *reinterpret_cast<const f4*>(W0f + q * 128 + c * 8);
      f4 w1 = *reinterpret_cast<const f4*>(W0f + q * 128 + c * 8 + 4);
#pragma unroll
      for (int jj = 0; jj < 4; ++jj) {
        h[jj]     = fmaf(fq, w0[jj], h[jj]);
        h[jj + 4] = fmaf(fq, w1[jj], h[jj + 4]);
      }
    }
    bf8 o;
#pragma unroll
    for (int jj = 0; jj < 8; ++jj) o[jj] = f2bf(fmaxf(h[jj], 0.f));
    *reinterpret_cast<bf8*>(sA + e * 128 + ((c ^ (e & 7)) << 3)) = o;
  }
  __syncthreads();                                    // A: h0 visible

  f4 acc[4][2];
  mfma_gemm<128>(sA, 16, WT1, c0, lane, b1v, acc);    // h1 = relu(h0)@W1+b1
  __syncthreads();                                    // B: all h0 reads done
  store_frags<true, true>(sA, 16, c0, lane, acc);     // h1 over h0 (in place)
  __syncthreads();                                    // C: h1 visible
  mfma_gemm<128>(sA, 16, WT2, c0, lane, b2v, acc);    // h2 = relu(h1)@W2+b2
  ln_rows(acc, lane, wave, sP);
  __syncthreads();                                    // D: sP ready, h1 reads done
  if (tid < 64) {
    float s = 0.f, qq = 0.f;
#pragma unroll
    for (int w = 0; w < 4; ++w) { s += sP[w * 64 + tid].x; qq += sP[w * 64 + tid].y; }
    float mean = s * (1.f / 128.f);
    float var = qq * (1.f / 128.f) - mean * mean;
    sStats[tid] = make_float2(mean, rsqrtf(var + 1e-5f));
  }
  __syncthreads();                                    // E

  // normalized h2 -> bf16 T tile in sA (col-rotated: conflict-free)
#pragma unroll
  for (int rf = 0; rf < 4; ++rf)
#pragma unroll
    for (int q = 0; q < 4; ++q) {
      int row = rf * 16 + ((lane >> 4) << 2) + q;
      float mean = sStats[row].x, rn = sStats[row].y;
#pragma unroll
      for (int cf = 0; cf < 2; ++cf) {
        int col = c0 + cf * 16 + (lane & 15);
        sA[row * 128 + ((col + 4 * row) & 127)] = f2bf((acc[rf][cf][q] - mean) * rn);
      }
    }
  __syncthreads();                                    // F

  // segmented column sums: one atomic per (j-run, col)
  {
    int grp = tid >> 7, c = tid & 127;
    int r0g = grp * 32;
    float accum = 0.f;
#pragma unroll 4
    for (int rr = r0g; rr < r0g + 32; ++rr) {
      accum += bf2f(sA[rr * 128 + ((c + 4 * rr) & 127)]);
      bool flush = (rr == r0g + 31) || (sJ[rr + 1] != sJ[rr]);
      if (flush) {
        unsafeAtomicAdd(agg + (size_t)sJ[rr] * 128 + c, accum);
        accum = 0.f;
      }
    }
  }
}

// ------------------------------------------------------------ node MLP ----
__global__ __launch_bounds__(256) void node_kernel(
    const float* __restrict__ x,
    const float* __restrict__ agg_m, const float* __restrict__ agg_c,
    const short* __restrict__ WT0, const float* __restrict__ b0v,
    const short* __restrict__ WT1, const float* __restrict__ b1v,
    const short* __restrict__ WT2, const float* __restrict__ b2v,
    float* __restrict__ out) {
  __shared__ __align__(16) short sA[64 * 384];
  __shared__ float2 sP[4 * 64];
  __shared__ float2 sStats[64];
  const int tid = threadIdx.x;
  const int lane = tid & 63, wave = tid >> 6;
  const int c0 = wave * 32;
  const int n0 = blockIdx.x * 64;

#pragma unroll
  for (int p = 0; p < 3; ++p) {
    const float* src = (p == 0) ? x : (p == 1) ? agg_m : agg_c;
#pragma unroll
    for (int it = 0; it < 4; ++it) {
      int s = it * 256 + tid;
      int e = s >> 4, cl = s & 15;
      int n = n0 + e;
      f4 u0 = {0.f, 0.f, 0.f, 0.f}, u1 = {0.f, 0.f, 0.f, 0.f};
      if (n < NN) {
        u0 = *reinterpret_cast<const f4*>(src + (size_t)n * 128 + cl * 8);
        u1 = *reinterpret_cast<const f4*>(src + (size_t)n * 128 + cl * 8 + 4);
      }
      bf8 o;
#pragma unroll
      for (int j = 0; j < 4; ++j) { o[j] = f2bf(u0[j]); o[j + 4] = f2bf(u1[j]); }
      int c = p * 16 + cl;
      *reinterpret_cast<bf8*>(sA + e * 384 + ((c ^ (e & 7)) << 3)) = o;
    }
  }
  __syncthreads();

  f4 acc[4][2];
  mfma_gemm<384>(sA, 48, WT0, c0, lane, b0v, acc);
  __syncthreads();
  store_frags<true, true>(sA, 16, c0, lane, acc);
  __syncthreads();
  mfma_gemm<128>(sA, 16, WT1, c0, lane, b1v, acc);
  __syncthreads();
  store_frags<true, true>(sA + 8192, 16, c0, lane, acc);
  __syncthreads();
  mfma_gemm<128>(sA + 8192, 16, WT2, c0, lane, b2v, acc);

  ln_rows(acc, lane, wave, sP);
  __syncthreads();
  if (tid < 64) {
    float s = 0.f, qq = 0.f;
#pragma unroll
    for (int w = 0; w < 4; ++w) { s += sP[w * 64 + tid].x; qq += sP[w * 64 + tid].y; }
    float mean = s * (1.f / 128.f);
    float var = qq * (1.f / 128.f) - mean * mean;
    sStats[tid] = make_float2(mean, rsqrtf(var + 1e-5f));
  }
  __syncthreads();

#pragma unroll
  for (int rf = 0; rf < 4; ++rf)
#pragma unroll
    for (int q = 0; q < 4; ++q) {
      int row = rf * 16 + ((lane >> 4) << 2) + q;
      int n = n0 + row;
      if (n < NN) {
        float mean = sStats[row].x, rn = sStats[row].y;
#pragma unroll
        for (int cf = 0; cf < 2; ++cf) {
          int col = c0 + cf * 16 + (lane & 15);
          float xv = x[(size_t)n * 128 + col];
          out[(size_t)n * 128 + col] = (acc[rf][cf][q] - mean) * rn + xv;
        }
      }
    }
}

// -------------------------------------------------------------- launch ----
extern "C" void kernel_launch(void* const* d_in, const int* in_sizes, int n_in,
                              void* d_out, int out_size, void* d_ws, size_t ws_size,
                              hipStream_t stream) {
  const float* x   = (const float*)d_in[0];
  const int*   g   = (const int*)d_in[1];
  const int*   cgr = (const int*)d_in[2];
  const float* pp  = (const float*)d_in[3];
  const float* mW0 = (const float*)d_in[4];
  const float* mb0 = (const float*)d_in[5];
  const float* mW1 = (const float*)d_in[6];
  const float* mb1 = (const float*)d_in[7];
  const float* mW2 = (const float*)d_in[8];
  const float* mb2 = (const float*)d_in[9];
  const float* cW0 = (const float*)d_in[10];
  const float* cb0 = (const float*)d_in[11];
  const float* cW1 = (const float*)d_in[12];
  const float* cb1 = (const float*)d_in[13];
  const float* cW2 = (const float*)d_in[14];
  const float* cb2 = (const float*)d_in[15];
  const float* nW0 = (const float*)d_in[16];
  const float* nb0 = (const float*)d_in[17];
  const float* nW1 = (const float*)d_in[18];
  const float* nb1 = (const float*)d_in[19];
  const float* nW2 = (const float*)d_in[20];
  const float* nb2 = (const float*)d_in[21];
  float* out = (float*)d_out;

  // ---- weight transpose packing (compute total size FIRST) ----
  WTDesc d;
  const float* srcs[11] = {mW1, mW2, cW1, cW2, nW0, nW1, nW2,
                           mW0 + 8 * 128, mW0 + 136 * 128, cW0 + 4 * 128, cW0 + 132 * 128};
  int Ks[11] = {128, 128, 128, 128, 384, 128, 128, 128, 128, 128, 128};
  int off = 0;
  for (int m = 0; m < 11; ++m) { d.src[m] = srcs[m]; d.K[m] = Ks[m]; d.off[m] = off; off += Ks[m] * 128; }

  // ---- workspace layout ----
  char* ws = (char*)d_ws;
  const size_t TBL = (size_t)NN * 128 * 2;        // 12.8 MB (bf16 table)
  const size_t AGG = (size_t)NN * 128 * 4;        // 25.6 MB (f32 agg)
  short* xa_m = (short*)(ws);
  short* xb_m = (short*)(ws + TBL);
  short* xa_c = (short*)(ws + 2 * TBL);
  short* xb_c = (short*)(ws + 3 * TBL);
  float* agg_m = (float*)(ws + 4 * TBL);
  float* agg_c = (float*)(ws + 4 * TBL + AGG);
  short* wt = (short*)(ws + 4 * TBL + 2 * AGG);
  char* ib = ws + 4 * TBL + 2 * AGG + (size_t)off * 2;   // after FULL wt buffer
  int* hist_m   = (int*)(ib);
  int* hist_c   = hist_m + NP;
  int* cursor_m = hist_c + NP;
  int* cursor_c = cursor_m + NP;
  int* tsum_m   = cursor_c + NP;
  int* tsum_c   = tsum_m + 128;
  int* si_m     = tsum_c + 128;
  int* sj_m     = si_m + NE_MAIN;
  int* si_c     = sj_m + NE_MAIN;
  int* sj_c     = si_c + NE_CONT;

  short* wt1_m = wt + d.off[0];
  short* wt2_m = wt + d.off[1];
  short* wt1_c = wt + d.off[2];
  short* wt2_c = wt + d.off[3];
  short* wtn0  = wt + d.off[4];
  short* wtn1  = wt + d.off[5];
  short* wtn2  = wt + d.off[6];
  short* wtp   = wt + d.off[7];

  const int NT = (NN + 511) / 512;   // 98 scan tiles per set

  wt_kernel<<<11 * 128, 128, 0, stream>>>(d, wt);
  zero2_kernel<<<2048, 256, 0, stream>>>((f4*)agg_m, (int)(2 * (size_t)NN * 128 / 4),
                                         (f4*)hist_m, 2 * NP / 4);

  // counting sort by j (both edge sets, merged launches)
  hist2_kernel<<<1024 + 256, 256, 0, stream>>>(g, cgr, hist_m, hist_c, 1024);
  scan1_kernel<<<2 * NT, 512, 0, stream>>>(hist_m, cursor_m, tsum_m,
                                           hist_c, cursor_c, tsum_c, NN, NT);
  scan2_kernel<<<2, 512, 0, stream>>>(tsum_m, tsum_c, NT);
  scan3_kernel<<<2 * NT, 512, 0, stream>>>(cursor_m, tsum_m, cursor_c, tsum_c, NN, NT);
  scatter2_kernel<<<1024 + 256, 256, 0, stream>>>(g, cgr, cursor_m, cursor_c,
                                                  si_m, sj_m, si_c, sj_c, 1024);

  precompute_kernel<<<(NN + 63) / 64, 256, 0, stream>>>(x, wtp, mb0, cb0,
                                                        xa_m, xb_m, xa_c, xb_c);

  edge_kernel<8><<<NE_MAIN / 64, 256, 0, stream>>>(si_m, sj_m, pp, xa_m, xb_m,
                                                   mW0, wt1_m, mb1, wt2_m, mb2, agg_m);
  edge_kernel<4><<<NE_CONT / 64, 256, 0, stream>>>(si_c, sj_c, pp, xa_c, xb_c,
                                                   cW0, wt1_c, cb1, wt2_c, cb2, agg_c);

  node_kernel<<<(NN + 63) / 64, 256, 0, stream>>>(x, agg_m, agg_c,
                                                  wtn0, nb0, wtn1, nb1, wtn2, nb2, out);
}